// Round 5
// baseline (145.929 us; speedup 1.0000x reference)
//
#include <hip/hip_runtime.h>
#include <hip/hip_bf16.h>
#include <stdint.h>

typedef unsigned short u16;
typedef __attribute__((ext_vector_type(8))) __bf16 bf16x8;
typedef __attribute__((ext_vector_type(4))) float f32x4;
typedef __attribute__((ext_vector_type(8))) u16 u16x8;

__device__ __forceinline__ u16 f2bf(float f) {
  union { float f; unsigned int u; } v; v.f = f;
  unsigned int r = v.u + 0x7fffu + ((v.u >> 16) & 1u);
  return (u16)(r >> 16);
}

__device__ __forceinline__ f32x4 mfma16(bf16x8 a, bf16x8 b, f32x4 c) {
  return __builtin_amdgcn_mfma_f32_16x16x32_bf16(a, b, c, 0, 0, 0);
}

__device__ __forceinline__ void gload16(const void* g, void* l) {
  __builtin_amdgcn_global_load_lds((const __attribute__((address_space(1))) void*)g,
                                   (__attribute__((address_space(3))) void*)l,
                                   16, 0, 0);
}

// ---------------- elementwise cast fp32 -> bf16 ----------------
__global__ void cast_bf16_kernel(const float* __restrict__ in, u16* __restrict__ out, int n) {
  int i = (blockIdx.x * 256 + threadIdx.x) * 8;
  if (i >= n) return;
  const float4* p = (const float4*)(in + i);
  float4 a = p[0], b = p[1];
  u16x8 o;
  o[0] = f2bf(a.x); o[1] = f2bf(a.y); o[2] = f2bf(a.z); o[3] = f2bf(a.w);
  o[4] = f2bf(b.x); o[5] = f2bf(b.y); o[6] = f2bf(b.z); o[7] = f2bf(b.w);
  *(u16x8*)(out + i) = o;
}

// ---------------- transpose + cast: in[R][C] fp32 -> out[C][R] bf16 ----------------
__global__ void transpose_cast_k(const float* __restrict__ in, u16* __restrict__ out,
                                 int R, int Ccols) {
  __shared__ float tile[64][65];
  const int c0 = (int)blockIdx.x << 6, r0 = (int)blockIdx.y << 6;
  const int tx = threadIdx.x & 63, ty = threadIdx.x >> 6;
#pragma unroll
  for (int i = ty; i < 64; i += 4)
    tile[i][tx] = in[(size_t)(r0 + i) * Ccols + c0 + tx];
  __syncthreads();
#pragma unroll
  for (int i = ty; i < 64; i += 4)
    out[(size_t)(c0 + i) * R + r0 + tx] = f2bf(tile[tx][i]);
}

// ---------------- GEMM: C[M][N] = A_bf16[M][K] @ Bt_bf16[N][K]^T + bias ----------------
__global__ __launch_bounds__(256, 2)
void gemm_bt(const u16* __restrict__ A, const u16* __restrict__ Bt,
             const float* __restrict__ bias, float* __restrict__ C,
             int M, int N, int K) {
  __shared__ u16 As[128 * 32];
  __shared__ u16 Bs[128 * 32];
  const int nb = N >> 7;
  const int m0 = (int)(blockIdx.x / nb) << 7;
  const int n0 = (int)(blockIdx.x % nb) << 7;
  const int tid = threadIdx.x;
  const int l = tid & 63, lg = l >> 4, ll = l & 15;
  const int w = tid >> 6;
  const int wr = (w >> 1) << 6, wc = (w & 1) << 6;
  const int srow = tid >> 2, scol = (tid & 3) << 3;
  const u16* ga = A + (size_t)(m0 + srow) * K + scol;
  const u16* gb = Bt + (size_t)(n0 + srow) * K + scol;
  u16* la0 = &As[srow * 32 + scol];
  u16* la1 = &As[(srow + 64) * 32 + scol];
  u16* lb0 = &Bs[srow * 32 + scol];
  u16* lb1 = &Bs[(srow + 64) * 32 + scol];
  const size_t K64 = (size_t)64 * K;
  f32x4 acc[4][4] = {};
  for (int kt = 0; kt < K; kt += 32) {
    gload16(ga + kt, la0);
    gload16(ga + kt + K64, la1);
    gload16(gb + kt, lb0);
    gload16(gb + kt + K64, lb1);
    __syncthreads();
    bf16x8 a[4], b[4];
#pragma unroll
    for (int i = 0; i < 4; ++i) {
      a[i] = *(const bf16x8*)&As[(wr + i * 16 + ll) * 32 + lg * 8];
      b[i] = *(const bf16x8*)&Bs[(wc + i * 16 + ll) * 32 + lg * 8];
    }
#pragma unroll
    for (int mi = 0; mi < 4; ++mi)
#pragma unroll
      for (int ni = 0; ni < 4; ++ni)
        acc[mi][ni] = mfma16(a[mi], b[ni], acc[mi][ni]);
    __syncthreads();
  }
#pragma unroll
  for (int mi = 0; mi < 4; ++mi) {
#pragma unroll
    for (int r = 0; r < 4; ++r) {
      const int row = m0 + wr + mi * 16 + lg * 4 + r;
      float* crow = C + (size_t)row * N + n0 + wc;
#pragma unroll
      for (int ni = 0; ni < 4; ++ni)
        crow[ni * 16 + ll] = acc[mi][ni][r] + bias[n0 + wc + ni * 16 + ll];
    }
  }
}

// ---------------- RoPE on q,k; split to head-major bf16; scale folded into q ----------------
__global__ void rope_split_k(const float* __restrict__ qkv,
                             const float* __restrict__ fc, const float* __restrict__ fs,
                             u16* __restrict__ qr, u16* __restrict__ kr) {
  const int t = blockIdx.x;
  const int b = t >> 11, s = t & 2047;
  const int h = threadIdx.x >> 5, i = threadIdx.x & 31;
  const float c = fc[s * 32 + i], sn = fs[s * 32 + i];
  const float* qp = qkv + (size_t)t * 3072 + (h << 6) + 2 * i;
  const float qe = qp[0], qo = qp[1];
  const float ke = qp[1024], ko = qp[1025];
  const size_t ob = (((size_t)((b << 4) + h) << 11) + s) * 64 + 2 * i;
  qr[ob]     = f2bf((qe * c - qo * sn) * 0.125f);
  qr[ob + 1] = f2bf((qe * sn + qo * c) * 0.125f);
  kr[ob]     = f2bf(ke * c - ko * sn);
  kr[ob + 1] = f2bf(ke * sn + ko * c);
}

// ---------------- V: qkv fp32 token-major -> vt[bh][d][s] bf16 (transposed) ----------------
__global__ void v_transpose_k(const float* __restrict__ qkv, u16* __restrict__ vt) {
  __shared__ float tile[64][65];
  const int bh = blockIdx.x;
  const int b = bh >> 4, h = bh & 15;
  const int s0 = (int)blockIdx.y << 6;
  const int tx = threadIdx.x & 63, ty = threadIdx.x >> 6;
#pragma unroll
  for (int i = ty; i < 64; i += 4)
    tile[i][tx] = qkv[(size_t)((b << 11) + s0 + i) * 3072 + 2048 + (h << 6) + tx];
  __syncthreads();
#pragma unroll
  for (int i = ty; i < 64; i += 4)
    vt[((size_t)(bh << 6) + i) * 2048 + s0 + tx] = f2bf(tile[tx][i]);
}

// ---------------- flash attention v4.1: 8 waves, 128 q-rows/block ----------------
// Same as v4 but with the causal-mask gate FIXED: mask whenever the chunk can
// contain any kv beyond the wave's FIRST row (kb+63 > q0). v4's gate
// (kb+63 > q0+15) skipped the diagonal chunk for the wave whose rows end
// exactly at the chunk boundary -> future-leakage on rows q0..q0+14.
__global__ __launch_bounds__(512, 2)
void attn_k(const u16* __restrict__ qr, const u16* __restrict__ kr,
            const u16* __restrict__ vt, u16* __restrict__ aout) {
  __shared__ __align__(16) char kvlds[16384];     // [0:8K) K tile, [8K:16K) V tile
  __shared__ __align__(16) u16 plds[8][16 * 72];  // wave-private P tiles
  const int bi = (int)blockIdx.x;
  const int bh = bi & 31;
  const int qt = (bi < 256) ? (15 - (bi >> 5)) : ((bi - 256) >> 5);
  const int tid = threadIdx.x;
  const int w = tid >> 6, l = tid & 63, lg = l >> 4, ll = l & 15;
  const u16* Q  = qr + (size_t)bh * (2048 * 64);
  const u16* Kp = kr + (size_t)bh * (2048 * 64);
  const u16* Vp = vt + (size_t)bh * (64 * 2048);
  const int q0 = (qt << 7) + w * 16;
  const bf16x8 qf0 = *(const bf16x8*)&Q[(q0 + ll) * 64 + lg * 8];
  const bf16x8 qf1 = *(const bf16x8*)&Q[(q0 + ll) * 64 + 32 + lg * 8];
  // staging: 512 threads, thread owns tile row sr = tid>>3, 16B at sc
  const int sr = tid >> 3, sc = (tid & 7) * 16;
  const int wo = (sr * 128 + sc) ^ ((sr & 7) << 4);
  const char* kga = (const char*)(Kp + (size_t)sr * 64) + sc;   // + ch*8192
  const char* vga = (const char*)(Vp + (size_t)sr * 2048) + sc; // + ch*128
  const int swz = (ll & 7) << 4;
  f32x4 o[4] = {};
  float mrow[4] = {-1e30f, -1e30f, -1e30f, -1e30f};
  float lp[4] = {0.f, 0.f, 0.f, 0.f};
  u16* myp = plds[w];
  const int nch = 2 * qt + 2;
  uint4 stgK = *(const uint4*)(kga);
  uint4 stgV = *(const uint4*)(vga);
  for (int ch = 0; ch < nch; ++ch) {
    asm volatile("s_waitcnt vmcnt(0)" ::: "memory");  // staged regs ready
    asm volatile("s_barrier" ::: "memory");           // prev compute done with LDS
    *(uint4*)(kvlds + wo) = stgK;
    *(uint4*)(kvlds + 8192 + wo) = stgV;
    if (ch + 1 < nch) {                               // issue next chunk early
      stgK = *(const uint4*)(kga + (size_t)(ch + 1) * 8192);
      stgV = *(const uint4*)(vga + (size_t)(ch + 1) * 128);
    }
    asm volatile("s_waitcnt lgkmcnt(0)" ::: "memory");
    asm volatile("s_barrier" ::: "memory");           // tiles visible to all waves
    // ---- QK^T from LDS ----
    f32x4 s4[4] = {};
#pragma unroll
    for (int c = 0; c < 4; ++c) {
      const int rb = (c * 16 + ll) * 128 + lg * 16;
      const bf16x8 kf0 = *(const bf16x8*)(kvlds + (rb ^ swz));
      const bf16x8 kf1 = *(const bf16x8*)(kvlds + ((rb + 64) ^ swz));
      s4[c] = mfma16(qf0, kf0, s4[c]);
      s4[c] = mfma16(qf1, kf1, s4[c]);
    }
    const int kb = ch << 6;
    if (kb + 63 > q0) {  // causal mask: chunk may contain kv beyond wave's first row
#pragma unroll
      for (int c = 0; c < 4; ++c)
#pragma unroll
        for (int r = 0; r < 4; ++r)
          if (kb + c * 16 + ll > q0 + lg * 4 + r) s4[c][r] = -1e30f;
    }
    // ---- online softmax ----
    float cm[4];
#pragma unroll
    for (int r = 0; r < 4; ++r)
      cm[r] = fmaxf(fmaxf(s4[0][r], s4[1][r]), fmaxf(s4[2][r], s4[3][r]));
#pragma unroll
    for (int d = 1; d < 16; d <<= 1)
#pragma unroll
      for (int r = 0; r < 4; ++r) cm[r] = fmaxf(cm[r], __shfl_xor(cm[r], d));
#pragma unroll
    for (int r = 0; r < 4; ++r) {
      const float mn = fmaxf(mrow[r], cm[r]);
      const float esc = __expf(mrow[r] - mn);
      mrow[r] = mn;
      lp[r] *= esc;
      o[0][r] *= esc; o[1][r] *= esc; o[2][r] *= esc; o[3][r] *= esc;
#pragma unroll
      for (int c = 0; c < 4; ++c) {
        const float p = __expf(s4[c][r] - mn);
        lp[r] += p;
        myp[(lg * 4 + r) * 72 + c * 16 + ll] = f2bf(p);
      }
    }
    asm volatile("s_waitcnt lgkmcnt(0)" ::: "memory");
    // ---- PV from LDS ----
    const bf16x8 pa0 = *(const bf16x8*)&myp[ll * 72 + lg * 8];
    const bf16x8 pa1 = *(const bf16x8*)&myp[ll * 72 + 32 + lg * 8];
#pragma unroll
    for (int v = 0; v < 4; ++v) {
      const int db = (v * 16 + ll) * 128 + lg * 16;
      const bf16x8 vf0 = *(const bf16x8*)(kvlds + 8192 + (db ^ swz));
      const bf16x8 vf1 = *(const bf16x8*)(kvlds + 8192 + ((db + 64) ^ swz));
      o[v] = mfma16(pa0, vf0, o[v]);
      o[v] = mfma16(pa1, vf1, o[v]);
    }
  }
  // deferred row-sum reduction
#pragma unroll
  for (int d = 1; d < 16; d <<= 1)
#pragma unroll
    for (int r = 0; r < 4; ++r) lp[r] += __shfl_xor(lp[r], d);
  const int hcol = (bh & 15) << 6;
  const int tokb = ((bh >> 4) << 11) + q0 + lg * 4;
#pragma unroll
  for (int r = 0; r < 4; ++r) {
    const float inv = 1.0f / lp[r];
    u16* orow = aout + (size_t)(tokb + r) * 1024 + hcol;
#pragma unroll
    for (int v = 0; v < 4; ++v)
      orow[v * 16 + ll] = f2bf(o[v][r] * inv);
  }
}

extern "C" void kernel_launch(void* const* d_in, const int* in_sizes, int n_in,
                              void* d_out, int out_size, void* d_ws, size_t ws_size,
                              hipStream_t stream) {
  const float* x    = (const float*)d_in[0];
  const float* fc   = (const float*)d_in[2];
  const float* fs   = (const float*)d_in[3];
  const float* Wqkv = (const float*)d_in[4];
  const float* bqkv = (const float*)d_in[5];
  const float* Wo   = (const float*)d_in[6];
  const float* bo   = (const float*)d_in[7];
  float* out = (float*)d_out;

  size_t off = 0;
  auto alloc = [&](size_t bytes) {
    void* p = (char*)d_ws + off;
    off += (bytes + 255) & ~(size_t)255;
    return p;
  };
  u16*   xb   = (u16*)  alloc(4096ull * 1024 * 2);
  u16*   wqt  = (u16*)  alloc(3072ull * 1024 * 2);
  u16*   wot  = (u16*)  alloc(1024ull * 1024 * 2);
  float* qkvf = (float*)alloc(4096ull * 3072 * 4);
  u16*   qr_  = (u16*)  alloc(32ull * 2048 * 64 * 2);
  u16*   kr_  = (u16*)  alloc(32ull * 2048 * 64 * 2);
  u16*   vt_  = (u16*)  alloc(32ull * 64 * 2048 * 2);
  u16*   ao_  = (u16*)  alloc(4096ull * 1024 * 2);

  cast_bf16_kernel<<<2048, 256, 0, stream>>>(x, xb, 4096 * 1024);
  transpose_cast_k<<<dim3(48, 16), 256, 0, stream>>>(Wqkv, wqt, 1024, 3072);
  transpose_cast_k<<<dim3(16, 16), 256, 0, stream>>>(Wo, wot, 1024, 1024);
  gemm_bt<<<dim3(32 * 24), 256, 0, stream>>>(xb, wqt, bqkv, qkvf, 4096, 3072, 1024);
  rope_split_k<<<dim3(4096), 512, 0, stream>>>(qkvf, fc, fs, qr_, kr_);
  v_transpose_k<<<dim3(32, 32), 256, 0, stream>>>(qkvf, vt_);
  attn_k<<<dim3(512), 512, 0, stream>>>(qr_, kr_, vt_, ao_);
  gemm_bt<<<dim3(32 * 8), 256, 0, stream>>>(ao_, wot, bo, out, 4096, 1024, 1024);
}

// Round 6
// 143.191 us; speedup vs baseline: 1.0191x; 1.0191x over previous
//
#include <hip/hip_runtime.h>
#include <hip/hip_bf16.h>
#include <stdint.h>

typedef unsigned short u16;
typedef __attribute__((ext_vector_type(8))) __bf16 bf16x8;
typedef __attribute__((ext_vector_type(4))) float f32x4;
typedef __attribute__((ext_vector_type(16))) float f32x16;
typedef __attribute__((ext_vector_type(8))) u16 u16x8;

__device__ __forceinline__ u16 f2bf(float f) {
  union { float f; unsigned int u; } v; v.f = f;
  unsigned int r = v.u + 0x7fffu + ((v.u >> 16) & 1u);
  return (u16)(r >> 16);
}
__device__ __forceinline__ unsigned pack2(float lo, float hi) {
  return (unsigned)f2bf(lo) | ((unsigned)f2bf(hi) << 16);
}

__device__ __forceinline__ f32x4 mfma16(bf16x8 a, bf16x8 b, f32x4 c) {
  return __builtin_amdgcn_mfma_f32_16x16x32_bf16(a, b, c, 0, 0, 0);
}
__device__ __forceinline__ f32x16 mfma32(bf16x8 a, bf16x8 b, f32x16 c) {
  return __builtin_amdgcn_mfma_f32_32x32x16_bf16(a, b, c, 0, 0, 0);
}

__device__ __forceinline__ void gload16(const void* g, void* l) {
  __builtin_amdgcn_global_load_lds((const __attribute__((address_space(1))) void*)g,
                                   (__attribute__((address_space(3))) void*)l,
                                   16, 0, 0);
}

// ---------------- elementwise cast fp32 -> bf16 ----------------
__global__ void cast_bf16_kernel(const float* __restrict__ in, u16* __restrict__ out, int n) {
  int i = (blockIdx.x * 256 + threadIdx.x) * 8;
  if (i >= n) return;
  const float4* p = (const float4*)(in + i);
  float4 a = p[0], b = p[1];
  u16x8 o;
  o[0] = f2bf(a.x); o[1] = f2bf(a.y); o[2] = f2bf(a.z); o[3] = f2bf(a.w);
  o[4] = f2bf(b.x); o[5] = f2bf(b.y); o[6] = f2bf(b.z); o[7] = f2bf(b.w);
  *(u16x8*)(out + i) = o;
}

// ---------------- transpose + cast: in[R][C] fp32 -> out[C][R] bf16 ----------------
__global__ void transpose_cast_k(const float* __restrict__ in, u16* __restrict__ out,
                                 int R, int Ccols) {
  __shared__ float tile[64][65];
  const int c0 = (int)blockIdx.x << 6, r0 = (int)blockIdx.y << 6;
  const int tx = threadIdx.x & 63, ty = threadIdx.x >> 6;
#pragma unroll
  for (int i = ty; i < 64; i += 4)
    tile[i][tx] = in[(size_t)(r0 + i) * Ccols + c0 + tx];
  __syncthreads();
#pragma unroll
  for (int i = ty; i < 64; i += 4)
    out[(size_t)(c0 + i) * R + r0 + tx] = f2bf(tile[tx][i]);
}

// ---------------- GEMM: C[M][N] = A_bf16[M][K] @ Bt_bf16[N][K]^T + bias ----------------
__global__ __launch_bounds__(256, 2)
void gemm_bt(const u16* __restrict__ A, const u16* __restrict__ Bt,
             const float* __restrict__ bias, float* __restrict__ C,
             int M, int N, int K) {
  __shared__ u16 As[128 * 32];
  __shared__ u16 Bs[128 * 32];
  const int nb = N >> 7;
  const int m0 = (int)(blockIdx.x / nb) << 7;
  const int n0 = (int)(blockIdx.x % nb) << 7;
  const int tid = threadIdx.x;
  const int l = tid & 63, lg = l >> 4, ll = l & 15;
  const int w = tid >> 6;
  const int wr = (w >> 1) << 6, wc = (w & 1) << 6;
  const int srow = tid >> 2, scol = (tid & 3) << 3;
  const u16* ga = A + (size_t)(m0 + srow) * K + scol;
  const u16* gb = Bt + (size_t)(n0 + srow) * K + scol;
  u16* la0 = &As[srow * 32 + scol];
  u16* la1 = &As[(srow + 64) * 32 + scol];
  u16* lb0 = &Bs[srow * 32 + scol];
  u16* lb1 = &Bs[(srow + 64) * 32 + scol];
  const size_t K64 = (size_t)64 * K;
  f32x4 acc[4][4] = {};
  for (int kt = 0; kt < K; kt += 32) {
    gload16(ga + kt, la0);
    gload16(ga + kt + K64, la1);
    gload16(gb + kt, lb0);
    gload16(gb + kt + K64, lb1);
    __syncthreads();
    bf16x8 a[4], b[4];
#pragma unroll
    for (int i = 0; i < 4; ++i) {
      a[i] = *(const bf16x8*)&As[(wr + i * 16 + ll) * 32 + lg * 8];
      b[i] = *(const bf16x8*)&Bs[(wc + i * 16 + ll) * 32 + lg * 8];
    }
#pragma unroll
    for (int mi = 0; mi < 4; ++mi)
#pragma unroll
      for (int ni = 0; ni < 4; ++ni)
        acc[mi][ni] = mfma16(a[mi], b[ni], acc[mi][ni]);
    __syncthreads();
  }
#pragma unroll
  for (int mi = 0; mi < 4; ++mi) {
#pragma unroll
    for (int r = 0; r < 4; ++r) {
      const int row = m0 + wr + mi * 16 + lg * 4 + r;
      float* crow = C + (size_t)row * N + n0 + wc;
#pragma unroll
      for (int ni = 0; ni < 4; ++ni)
        crow[ni * 16 + ll] = acc[mi][ni][r] + bias[n0 + wc + ni * 16 + ll];
    }
  }
}

// ---------------- RoPE on q,k; split to head-major bf16; scale folded into q ----------------
__global__ void rope_split_k(const float* __restrict__ qkv,
                             const float* __restrict__ fc, const float* __restrict__ fs,
                             u16* __restrict__ qr, u16* __restrict__ kr) {
  const int t = blockIdx.x;
  const int b = t >> 11, s = t & 2047;
  const int h = threadIdx.x >> 5, i = threadIdx.x & 31;
  const float c = fc[s * 32 + i], sn = fs[s * 32 + i];
  const float* qp = qkv + (size_t)t * 3072 + (h << 6) + 2 * i;
  const float qe = qp[0], qo = qp[1];
  const float ke = qp[1024], ko = qp[1025];
  const size_t ob = (((size_t)((b << 4) + h) << 11) + s) * 64 + 2 * i;
  qr[ob]     = f2bf((qe * c - qo * sn) * 0.125f);
  qr[ob + 1] = f2bf((qe * sn + qo * c) * 0.125f);
  kr[ob]     = f2bf(ke * c - ko * sn);
  kr[ob + 1] = f2bf(ke * sn + ko * c);
}

// ---------------- V: qkv fp32 token-major -> vt[bh][d][s] bf16 (transposed) ----------------
__global__ void v_transpose_k(const float* __restrict__ qkv, u16* __restrict__ vt) {
  __shared__ float tile[64][65];
  const int bh = blockIdx.x;
  const int b = bh >> 4, h = bh & 15;
  const int s0 = (int)blockIdx.y << 6;
  const int tx = threadIdx.x & 63, ty = threadIdx.x >> 6;
#pragma unroll
  for (int i = ty; i < 64; i += 4)
    tile[i][tx] = qkv[(size_t)((b << 11) + s0 + i) * 3072 + 2048 + (h << 6) + tx];
  __syncthreads();
#pragma unroll
  for (int i = ty; i < 64; i += 4)
    vt[((size_t)(bh << 6) + i) * 2048 + s0 + tx] = f2bf(tile[tx][i]);
}

// ---------------- flash attention v5: swapped-operand, in-register softmax ----------------
// 4 waves x 32 q-rows = 128 q/block. KVBLK=64, 32x32x16 MFMA.
// S^T = mfma(A=K, B=Q): lane holds 32 S values for ONE q (q=lane&31, kv in
// regs, lane-half hi splits kv by +4). Softmax fully in-register: local max
// over 32 regs + one shfl_xor(32). P packed to bf16 in-register, redistributed
// across lane-halves (shfl_xor(32)+select), fed straight to PV as B-operand:
// O^T = mfma(A=V^T, B=P). No P LDS round-trip, no shfl trees.
// K/V staging identical to v3 (proven): swizzled, async-stage pipelined.
__global__ __launch_bounds__(256, 2)
void attn_k(const u16* __restrict__ qr, const u16* __restrict__ kr,
            const u16* __restrict__ vt, u16* __restrict__ aout) {
  __shared__ __align__(16) char kvlds[16384];     // [0:8K) K tile, [8K:16K) V^T tile
  const int bi = (int)blockIdx.x;
  const int bh = bi & 31;
  const int qt = (bi < 256) ? (15 - (bi >> 5)) : ((bi - 256) >> 5);
  const int tid = threadIdx.x;
  const int w = tid >> 6, l = tid & 63, hi = l >> 5, ql = l & 31;
  const u16* Q  = qr + (size_t)bh * (2048 * 64);
  const u16* Kp = kr + (size_t)bh * (2048 * 64);
  const u16* Vp = vt + (size_t)bh * (64 * 2048);
  const int q0w = (qt << 7) + (w << 5);
  const int qg = q0w + ql;                       // this lane's q row
  bf16x8 qf[4];                                  // Q[qg][16*mi + 8*hi .. +8]
#pragma unroll
  for (int mi = 0; mi < 4; ++mi)
    qf[mi] = *(const bf16x8*)&Q[(size_t)qg * 64 + mi * 16 + hi * 8];
  // staging: thread owns tile row sr, bytes sc..sc+31 (2x16B), XOR-swizzled
  const int sr = tid >> 2, sc = (tid & 3) * 32;
  const int wo0 = (sr * 128 + sc) ^ ((sr & 7) << 4);
  const int wo1 = (sr * 128 + sc + 16) ^ ((sr & 7) << 4);
  const char* kga = (const char*)(Kp + (size_t)sr * 64) + sc;   // + ch*8192
  const char* vga = (const char*)(Vp + (size_t)sr * 2048) + sc; // + ch*128
  const int swz = (ql & 7) << 4;
  f32x16 oa = {}, ob = {};                       // O^T d=ql(+4hi pattern) / 32+...
  float mrow = -1e30f, lp = 0.f;
  const int nch = 2 * qt + 2;
  uint4 sk0 = *(const uint4*)(kga), sk1 = *(const uint4*)(kga + 16);
  uint4 sv0 = *(const uint4*)(vga), sv1 = *(const uint4*)(vga + 16);
  for (int ch = 0; ch < nch; ++ch) {
    asm volatile("s_waitcnt vmcnt(0)" ::: "memory");  // staged regs ready
    asm volatile("s_barrier" ::: "memory");           // prev compute done with LDS
    *(uint4*)(kvlds + wo0) = sk0;
    *(uint4*)(kvlds + wo1) = sk1;
    *(uint4*)(kvlds + 8192 + wo0) = sv0;
    *(uint4*)(kvlds + 8192 + wo1) = sv1;
    if (ch + 1 < nch) {                               // issue next chunk early
      const size_t kof = (size_t)(ch + 1) * 8192;
      const size_t vof = (size_t)(ch + 1) * 128;
      sk0 = *(const uint4*)(kga + kof); sk1 = *(const uint4*)(kga + kof + 16);
      sv0 = *(const uint4*)(vga + vof); sv1 = *(const uint4*)(vga + vof + 16);
    }
    asm volatile("s_waitcnt lgkmcnt(0)" ::: "memory");
    asm volatile("s_barrier" ::: "memory");           // tiles visible to all waves
    const int kb = ch << 6;
    if (kb > q0w + 31) continue;   // fully masked for this wave (barriers done)
    // ---- QK^T swapped: S^T[kv][q], two 32-kv sub-blocks ----
    f32x16 s0 = {}, s1 = {};
#pragma unroll
    for (int mi = 0; mi < 4; ++mi) {
      const int cb = mi * 32 + hi * 16;
      const bf16x8 k0 = *(const bf16x8*)(kvlds + ((ql * 128 + cb) ^ swz));
      const bf16x8 k1 = *(const bf16x8*)(kvlds + (((32 + ql) * 128 + cb) ^ swz));
      s0 = mfma32(k0, qf[mi], s0);
      s1 = mfma32(k1, qf[mi], s1);
    }
    // ---- causal mask (lane's q is fixed; kv is per-reg, compile-time offsets) ----
    if (kb + 63 > q0w) {
#pragma unroll
      for (int r = 0; r < 16; ++r) {
        const int kvo = (r & 3) + 8 * (r >> 2) + 4 * hi;
        if (kb + kvo > qg) s0[r] = -1e30f;
        if (kb + 32 + kvo > qg) s1[r] = -1e30f;
      }
    }
    // ---- in-register online softmax ----
    float mx = s0[0];
#pragma unroll
    for (int r = 1; r < 16; ++r) mx = fmaxf(mx, s0[r]);
#pragma unroll
    for (int r = 0; r < 16; ++r) mx = fmaxf(mx, s1[r]);
    mx = fmaxf(mx, __shfl_xor(mx, 32));
    if (!__all(mx <= mrow + 8.f)) {   // defer-max: skip rescale on small growth
      const float mn = fmaxf(mrow, mx);
      const float esc = __expf(mrow - mn);
      mrow = mn;
      lp *= esc;
#pragma unroll
      for (int r = 0; r < 16; ++r) { oa[r] *= esc; ob[r] *= esc; }
    }
    float p0[16], p1[16];
#pragma unroll
    for (int r = 0; r < 16; ++r) {
      p0[r] = __expf(s0[r] - mrow);
      p1[r] = __expf(s1[r] - mrow);
      lp += p0[r] + p1[r];
    }
    // ---- pack P to bf16 B-frags (lane-half redistribution via shfl_xor 32) ----
    bf16x8 pb[4];
#pragma unroll
    for (int s = 0; s < 2; ++s) {
      const float* ps = s ? p1 : p0;
#pragma unroll
      for (int j = 0; j < 2; ++j) {
        const unsigned X0 = pack2(ps[j * 8 + 0], ps[j * 8 + 1]);
        const unsigned X1 = pack2(ps[j * 8 + 2], ps[j * 8 + 3]);
        const unsigned Y0 = pack2(ps[j * 8 + 4], ps[j * 8 + 5]);
        const unsigned Y1 = pack2(ps[j * 8 + 6], ps[j * 8 + 7]);
        const unsigned sX0 = (unsigned)__shfl_xor((int)X0, 32);
        const unsigned sX1 = (unsigned)__shfl_xor((int)X1, 32);
        const unsigned sY0 = (unsigned)__shfl_xor((int)Y0, 32);
        const unsigned sY1 = (unsigned)__shfl_xor((int)Y1, 32);
        union { unsigned u[4]; bf16x8 v; } t;
        t.u[0] = hi ? sY0 : X0;   // k=8hi+{0,1}
        t.u[1] = hi ? sY1 : X1;   // k=8hi+{2,3}
        t.u[2] = hi ? Y0 : sX0;   // k=8hi+{4,5}
        t.u[3] = hi ? Y1 : sX1;   // k=8hi+{6,7}
        pb[s * 2 + j] = t.v;
      }
    }
    // ---- PV swapped: O^T[d][q] += mfma(A=V^T, B=P) ----
#pragma unroll
    for (int jj = 0; jj < 4; ++jj) {
      const int cb = jj * 32 + hi * 16;
      const bf16x8 va = *(const bf16x8*)(kvlds + 8192 + ((ql * 128 + cb) ^ swz));
      const bf16x8 vb = *(const bf16x8*)(kvlds + 8192 + (((32 + ql) * 128 + cb) ^ swz));
      oa = mfma32(va, pb[jj], oa);
      ob = mfma32(vb, pb[jj], ob);
    }
  }
  // ---- epilogue: combine lane-halves' sums, normalize, write O ----
  lp += __shfl_xor(lp, 32);
  const float inv = 1.0f / lp;
  const int hcol = (bh & 15) << 6;
  const int tok = ((bh >> 4) << 11) + qg;
  unsigned* orow = (unsigned*)(aout + (size_t)tok * 1024 + hcol);
#pragma unroll
  for (int r = 0; r < 16; r += 2) {
    const int d0 = (r & 3) + 8 * (r >> 2) + 4 * hi;   // even; pairs (d0, d0+1)
    orow[d0 >> 1]        = pack2(oa[r] * inv, oa[r + 1] * inv);
    orow[(32 + d0) >> 1] = pack2(ob[r] * inv, ob[r + 1] * inv);
  }
}

extern "C" void kernel_launch(void* const* d_in, const int* in_sizes, int n_in,
                              void* d_out, int out_size, void* d_ws, size_t ws_size,
                              hipStream_t stream) {
  const float* x    = (const float*)d_in[0];
  const float* fc   = (const float*)d_in[2];
  const float* fs   = (const float*)d_in[3];
  const float* Wqkv = (const float*)d_in[4];
  const float* bqkv = (const float*)d_in[5];
  const float* Wo   = (const float*)d_in[6];
  const float* bo   = (const float*)d_in[7];
  float* out = (float*)d_out;

  size_t off = 0;
  auto alloc = [&](size_t bytes) {
    void* p = (char*)d_ws + off;
    off += (bytes + 255) & ~(size_t)255;
    return p;
  };
  u16*   xb   = (u16*)  alloc(4096ull * 1024 * 2);
  u16*   wqt  = (u16*)  alloc(3072ull * 1024 * 2);
  u16*   wot  = (u16*)  alloc(1024ull * 1024 * 2);
  float* qkvf = (float*)alloc(4096ull * 3072 * 4);
  u16*   qr_  = (u16*)  alloc(32ull * 2048 * 64 * 2);
  u16*   kr_  = (u16*)  alloc(32ull * 2048 * 64 * 2);
  u16*   vt_  = (u16*)  alloc(32ull * 64 * 2048 * 2);
  u16*   ao_  = (u16*)  alloc(4096ull * 1024 * 2);

  cast_bf16_kernel<<<2048, 256, 0, stream>>>(x, xb, 4096 * 1024);
  transpose_cast_k<<<dim3(48, 16), 256, 0, stream>>>(Wqkv, wqt, 1024, 3072);
  transpose_cast_k<<<dim3(16, 16), 256, 0, stream>>>(Wo, wot, 1024, 1024);
  gemm_bt<<<dim3(32 * 24), 256, 0, stream>>>(xb, wqt, bqkv, qkvf, 4096, 3072, 1024);
  rope_split_k<<<dim3(4096), 512, 0, stream>>>(qkvf, fc, fs, qr_, kr_);
  v_transpose_k<<<dim3(32, 32), 256, 0, stream>>>(qkvf, vt_);
  attn_k<<<dim3(512), 256, 0, stream>>>(qr_, kr_, vt_, ao_);
  gemm_bt<<<dim3(32 * 8), 256, 0, stream>>>(ao_, wot, bo, out, 4096, 1024, 1024);
}